// Round 18
// baseline (50.075 us; speedup 1.0000x reference)
//
#include <hip/hip_runtime.h>

#define NQ 12
#define NL 4

typedef float f32x2 __attribute__((ext_vector_type(2)));

// ---------------------------------------------------------------------------
// Compile-time CNOT tracking as a GF(2) linear map (rounds 1-17, verified).
// RY(l,q) in tan form: mine'[i] = mine[i] + T(i)*mine[i^mk],
//   T(i) = +t iff parity(rm & i) odd else -t; cos factors -> Ctot^2 at end.
// LAYOUT (r9-r17, verified): TWO batch elements per wave.
//   physical lane = (elem << 5) | l5;  global index i = (l5 << 7) | (r<<1) | h
// ROUND 18 (on r17 base): (1) masks {5,10} DS -> 2-DPP (r9-verified set;
// post-r17 a DPP fetch is 1 op, flipping the r10-era economics; DS/wave
// 664->408); (2) mixed single-DPP gates packed (2 movs + 1 pk_fma / reg);
// (3) no __syncthreads — prep slab is per-wave (same-wave DS is in-order),
// barrier only forced lockstep + waitcnt drain.
// ---------------------------------------------------------------------------
struct MaskTab { int mk[NL][NQ]; int rm[NL][NQ]; int rout[NQ]; };

static constexpr MaskTab build_masks() {
  MaskTab T{};
  unsigned col[NQ] = {};
  unsigned inv[NQ] = {};
  for (int k = 0; k < NQ; ++k) { col[k] = 1u << k; inv[k] = 1u << k; }
  for (int l = 0; l < NL; ++l) {
    for (int q = 0; q < NQ; ++q) {
      const int p = NQ - 1 - q;
      T.mk[l][q] = (int)inv[p];
      int rm = 0;
      for (int k = 0; k < NQ; ++k) rm |= (int)(((col[k] >> p) & 1u) << k);
      T.rm[l][q] = rm;
    }
    for (int q = 0; q < NQ - 1; ++q) {
      const int pc = NQ - 1 - q, pt = NQ - 2 - q;
      for (int k = 0; k < NQ; ++k) col[k] ^= ((col[k] >> pc) & 1u) << pt;
      inv[pc] ^= inv[pt];
    }
  }
  for (int q = 0; q < NQ; ++q) {
    const int p = NQ - 1 - q;
    int rm = 0;
    for (int k = 0; k < NQ; ++k) rm |= (int)(((col[k] >> p) & 1u) << k);
    T.rout[q] = rm;
  }
  return T;
}
static constexpr MaskTab MT = build_masks();

// ---------------- compile-time utils ----------------
constexpr int cpar(int j, int m) { return __builtin_popcount((unsigned)(j & m)) & 1; }
constexpr int chb(int m) { return m ? (1 << (31 - __builtin_clz((unsigned)m))) : 0; }
constexpr bool dpp_ok(int d) { return d==1||d==2||d==3||d==7||d==8||d==15; }
constexpr int dpp_ctrl_for(int d) {
  return d==1?0xB1 : d==2?0x4E : d==3?0x1B : d==7?0x141 : d==8?0x128 : 0x140;
}
// 2-DPP XOR compositions (r9-verified set): 5=7^2, 6=7^1, 10=8^2, 12=15^3
constexpr bool synth2_ok(int d) { return d==5||d==6||d==10||d==12; }
constexpr int synth_a(int d) { return d==5?0x141 : d==6?0x141 : d==10?0x128 : 0x140; }
constexpr int synth_b(int d) { return d==5?0x4E  : d==6?0xB1  : d==10?0x4E  : 0x1B; }

template <int V> struct ic_ { static constexpr int v = V; };
template <int I, int N, typename F>
__device__ __forceinline__ void sfor(F&& f) {
  if constexpr (I < N) { f(ic_<I>{}); sfor<I + 1, N>(f); }
}

// ---------------- cross-lane primitives ----------------
// r17-verified: single-instruction DPP mov (all source lanes active).
template <int CTRL>
__device__ __forceinline__ float dppf(float x) {
  return __int_as_float(__builtin_amdgcn_mov_dpp(__float_as_int(x), CTRL, 0xF, 0xF, false));
}
template <int PAT>
__device__ __forceinline__ float swzf(float x) {
  return __int_as_float(__builtin_amdgcn_ds_swizzle(__float_as_int(x), PAT));
}

__device__ __forceinline__ f32x2 pfma(f32x2 t, f32x2 p, f32x2 s) {
  return __builtin_elementwise_fma(t, p, s);
}

// lane-parity base sign: odd parity -> +t, even -> -t (rounds 2-17 verified).
template <int MASK>
__device__ __forceinline__ float lane_sign(float t, int lane) {
  if constexpr (MASK == 0) return -t;
  else return (__popc(lane & MASK) & 1) ? t : -t;
}

// ---------------- one RY gate (tan form), 2-elem layout ----------------
template <int L, int Q>
__device__ __forceinline__ void gate(f32x2 (&s2)[64], float t, int lane) {
  constexpr int MK  = MT.mk[L][Q];
  constexpr int RM  = MT.rm[L][Q];
  constexpr int MKL = (MK >> 7) & 31;   // lane-xor (physical lane bits 0-4)
  constexpr int MKO = MK & 127;         // register+half xor (index bits 0-6)
  constexpr int RMH = (RM >> 7) & 31;
  constexpr int RMO = RM & 127;
  const float tl  = lane_sign<RMH>(t, lane);
  const float tln = -tl;
  constexpr int M2 = MKO >> 1;   // f32x2-register xor
  constexpr int HS = MKO & 1;    // half swap (index bit 0)

  if constexpr (MKL == 0 && HS == 0) {
    // ---- packed register butterfly; RMO even -> per-register uniform sign ----
    f32x2 tp; tp.x = tl;  tp.y = tl;
    f32x2 tn; tn.x = tln; tn.y = tln;
    constexpr int HB = chb(M2);
    sfor<0, 64>([&](auto RC) {
      constexpr int r0 = decltype(RC)::v;
      if constexpr ((r0 & HB) == 0) {
        constexpr int r1 = r0 ^ M2;
        const f32x2 A = s2[r0], B = s2[r1];
        s2[r0] = pfma(cpar(2*r0, RMO) ? tn : tp, B, A);
        s2[r1] = pfma(cpar(2*r1, RMO) ? tn : tp, A, B);
      }
    });
  } else if constexpr (MKL == 0) {
    // ---- half-swap register gates: scalar FMAs ----
    if constexpr (M2 == 0) {
      sfor<0, 64>([&](auto RC) {
        constexpr int r = decltype(RC)::v;
        const float ax = s2[r].x, ay = s2[r].y;
        s2[r].x = fmaf(cpar(2*r,   RMO) ? tln : tl, ay, ax);
        s2[r].y = fmaf(cpar(2*r+1, RMO) ? tln : tl, ax, ay);
      });
    } else {
      constexpr int HB = chb(M2);
      sfor<0, 64>([&](auto RC) {
        constexpr int r0 = decltype(RC)::v;
        if constexpr ((r0 & HB) == 0) {
          constexpr int r1 = r0 ^ M2;
          const float ax = s2[r0].x, ay = s2[r0].y;
          const float bx = s2[r1].x, by = s2[r1].y;
          s2[r0].x = fmaf(cpar(2*r0,   RMO) ? tln : tl, by, ax);
          s2[r0].y = fmaf(cpar(2*r0+1, RMO) ? tln : tl, bx, ay);
          s2[r1].x = fmaf(cpar(2*r1,   RMO) ? tln : tl, ay, bx);
          s2[r1].y = fmaf(cpar(2*r1+1, RMO) ? tln : tl, ax, by);
        }
      });
    }
  } else if constexpr ((dpp_ok(MKL) || synth2_ok(MKL)) && MKO == 0) {
    // ---- pure DPP-path gates: scalar tied-dst form (fmac_dpp fusion) ----
    auto D = [&](float x) -> float {
      if constexpr (dpp_ok(MKL)) return dppf<dpp_ctrl_for(MKL)>(x);
      else return dppf<synth_b(MKL)>(dppf<synth_a(MKL)>(x));
    };
    sfor<0, 64>([&](auto RC) {
      constexpr int r = decltype(RC)::v;
      const float sr = cpar(2*r, RMO) ? tln : tl;
      s2[r].x = fmaf(D(s2[r].x), sr, s2[r].x);
      s2[r].y = fmaf(D(s2[r].y), sr, s2[r].y);
    });
  } else if constexpr (dpp_ok(MKL) || synth2_ok(MKL)) {
    // ---- mixed DPP gates: packed (2 movs + 1 pk_fma per register) ----
    auto D = [&](float x) -> float {
      if constexpr (dpp_ok(MKL)) return dppf<dpp_ctrl_for(MKL)>(x);
      else return dppf<synth_b(MKL)>(dppf<synth_a(MKL)>(x));
    };
    f32x2 tp; tp.x = tl;  tp.y = tl;
    f32x2 tn; tn.x = tln; tn.y = tln;
    constexpr int HB = chb(M2);
    sfor<0, 64>([&](auto RC) {
      constexpr int r0 = decltype(RC)::v;
      if constexpr ((r0 & HB) == 0) {
        constexpr int r1 = r0 ^ M2;
        f32x2 pa; pa.x = D(s2[r1].x); pa.y = D(s2[r1].y);
        f32x2 pb; pb.x = D(s2[r0].x); pb.y = D(s2[r0].y);
        s2[r0] = pfma(cpar(2*r0, RMO) ? tn : tp, pa, s2[r0]);
        s2[r1] = pfma(cpar(2*r1, RMO) ? tn : tp, pb, s2[r1]);
      }
    });
  } else {
    // ---- DS swizzle cross gates (lane masks with bit 4: 20, 24, 30) ----
    constexpr int PAT = (MKL << 10) | 0x1F;
    f32x2 tp; tp.x = tl;  tp.y = tl;
    f32x2 tn; tn.x = tln; tn.y = tln;
    if constexpr (M2 == 0) {
      sfor<0, 64>([&](auto RC) {
        constexpr int r = decltype(RC)::v;
        f32x2 p; p.x = swzf<PAT>(s2[r].x); p.y = swzf<PAT>(s2[r].y);
        s2[r] = pfma(cpar(2*r, RMO) ? tn : tp, p, s2[r]);
      });
    } else {
      constexpr int HB = chb(M2);
      sfor<0, 64>([&](auto RC) {
        constexpr int r0 = decltype(RC)::v;
        if constexpr ((r0 & HB) == 0) {
          constexpr int r1 = r0 ^ M2;
          f32x2 pa; pa.x = swzf<PAT>(s2[r1].x); pa.y = swzf<PAT>(s2[r1].y);
          f32x2 pb; pb.x = swzf<PAT>(s2[r0].x); pb.y = swzf<PAT>(s2[r0].y);
          s2[r0] = pfma(cpar(2*r0, RMO) ? tn : tp, pa, s2[r0]);
          s2[r1] = pfma(cpar(2*r1, RMO) ? tn : tp, pb, s2[r1]);
        }
      });
    }
  }
}

template <int L, int Q>
__device__ __forceinline__ void round_rec(f32x2 (&s2)[64], const float (&t)[NQ], int lane) {
  if constexpr (Q < NQ) {
    gate<L, Q>(s2, t[Q], lane);
    round_rec<L, Q + 1>(s2, t, lane);
  }
}

__global__ __launch_bounds__(256, 2) void vqc_kernel(const float* __restrict__ ang,
                                                     const float* __restrict__ thetas,
                                                     float* __restrict__ out, int B) {
  const int tid  = blockIdx.x * blockDim.x + threadIdx.x;
  const int gw   = tid >> 6;          // wave index: elements 2gw, 2gw+1
  const int lane = tid & 63;
  const int l5   = lane & 31;
  const int elem = lane >> 5;
  const int row_store = 2 * gw + elem;
  const int row = (row_store < B) ? row_store : (B - 1);   // clamp

  // ---- distributed angle prep -> per-WAVE LDS slab (r10/r11 verified) ----
  // Same-wave write->read: DS ops from one wave execute in order; no barrier.
  // slab per element (64 floats): [0..35] tan(l=1..3,q), [36..47] c0, [48..59] s0
  __shared__ float prep[4][2][64];
  const int wib = threadIdx.x >> 6;
  float* P = &prep[wib][elem][0];

  float csprod;
  {
    const int tau1 = l5;
    const int lq1 = (1 + tau1 / 12) * NQ + (tau1 % 12);
    float sn, cs;
    __sincosf(0.5f * (ang[row * NQ + (tau1 % 12)] + thetas[lq1]), &sn, &cs);
    P[tau1] = __fdividef(sn, cs);
    csprod = cs;
    if (l5 < 16) {
      const int tau2 = l5 + 32;
      if (tau2 < 36) {
        const int q2 = tau2 % 12;
        float sn2, cs2;
        __sincosf(0.5f * (ang[row * NQ + q2] + thetas[3 * NQ + q2]), &sn2, &cs2);
        P[tau2] = __fdividef(sn2, cs2);
        csprod *= cs2;
      } else {
        const int q2 = tau2 - 36;
        float sn2, cs2;
        __sincosf(0.5f * (ang[row * NQ + q2] + thetas[q2]), &sn2, &cs2);
        P[36 + q2] = cs2;
        P[48 + q2] = sn2;
      }
    }
    csprod *= dppf<0xB1>(csprod);
    csprod *= dppf<0x4E>(csprod);
    csprod *= swzf<(4 << 10) | 0x1F>(csprod);
    csprod *= dppf<0x128>(csprod);
    csprod *= swzf<(16 << 10) | 0x1F>(csprod);
  }
  const float Csq = csprod * csprod;

  // vector read-back (broadcast reads, conflict-free; same-wave ordering)
  float t1[NQ], t2[NQ], t3[NQ], c0[NQ], s0[NQ];
  {
    const float4* P4 = (const float4*)P;
#define LD4(arr, base, idx) { float4 v = P4[idx]; arr[base]=v.x; arr[base+1]=v.y; arr[base+2]=v.z; arr[base+3]=v.w; }
    LD4(t1, 0, 0) LD4(t1, 4, 1) LD4(t1, 8, 2)
    LD4(t2, 0, 3) LD4(t2, 4, 4) LD4(t2, 8, 5)
    LD4(t3, 0, 6) LD4(t3, 4, 7) LD4(t3, 8, 8)
    LD4(c0, 0, 9) LD4(c0, 4, 10) LD4(c0, 8, 11)
    LD4(s0, 0, 12) LD4(s0, 4, 13) LD4(s0, 8, 14)
#undef LD4
  }

  // ---- layer 0 on |0..0>: per-element product state (rounds 9-17 verified) ----
  float flane = 1.0f;
  #pragma unroll
  for (int k = 0; k < 5; ++k) {
    flane *= ((l5 >> k) & 1) ? s0[4 - k] : c0[4 - k];
  }
  f32x2 s2[64];
  { f32x2 h0; h0.x = c0[11] * flane; h0.y = s0[11] * flane; s2[0] = h0; }
  #pragma unroll
  for (int k = 0; k < 6; ++k) {
    const int W = 1 << k;
    #pragma unroll
    for (int j = 0; j < 64; ++j) {
      if (j >= W) continue;
      s2[j + W] = s2[j] * s0[10 - k];
      s2[j]     = s2[j] * c0[10 - k];
    }
  }

  // ---- layers 1-3 (tan form) ----
  round_rec<1, 0>(s2, t1, lane);
  round_rec<2, 0>(s2, t2, lane);
  round_rec<3, 0>(s2, t3, lane);

  // probabilities (unscaled, packed)
  #pragma unroll
  for (int r = 0; r < 64; ++r) s2[r] = s2[r] * s2[r];

  // Walsh-Hadamard over the 7 register-dim bits
  #pragma unroll
  for (int r = 0; r < 64; ++r) {
    const float u = s2[r].x, v = s2[r].y;
    s2[r].x = u + v;
    s2[r].y = u - v;
  }
  #pragma unroll
  for (int b = 0; b < 6; ++b) {
    const int W = 1 << b;
    #pragma unroll
    for (int r0 = 0; r0 < 64; ++r0) {
      if (r0 & W) continue;
      const int r1 = r0 | W;
      const f32x2 u = s2[r0], v = s2[r1];
      s2[r0] = u + v;
      s2[r1] = u - v;
    }
  }

  // ---- epilogue: 12 signed reductions over lane bits 0-4 (per element) ----
  sfor<0, NQ>([&](auto QC) {
    constexpr int q   = decltype(QC)::v;
    constexpr int RM  = MT.rout[q];
    constexpr int RMH = (RM >> 7) & 31;
    constexpr int RMO = RM & 127;
    float v = (RMO & 1) ? s2[RMO >> 1].y : s2[RMO >> 1].x;
    if constexpr (RMH != 0) {
      const int sx = (__popc(lane & RMH) & 1) << 31;  // odd lane parity -> minus
      v = __int_as_float(__float_as_int(v) ^ sx);
    }
    v += dppf<0xB1>(v);               // xor1
    v += dppf<0x4E>(v);               // xor2
    v += swzf<(4 << 10) | 0x1F>(v);   // xor4
    v += dppf<0x128>(v);              // xor8
    v += swzf<(16 << 10) | 0x1F>(v);  // xor16 (within 32-lane group)
    if (l5 == 0 && row_store < B) out[row_store * NQ + q] = v * Csq;
  });
}

extern "C" void kernel_launch(void* const* d_in, const int* in_sizes, int n_in,
                              void* d_out, int out_size, void* d_ws, size_t ws_size,
                              hipStream_t stream) {
  const float* ang    = (const float*)d_in[0];
  const float* thetas = (const float*)d_in[1];
  float* out          = (float*)d_out;
  const int B = in_sizes[0] / NQ;
  const int waves = (B + 1) / 2;       // 2 elements per wave
  const int threads = 256;
  const int blocks = (waves * 64 + threads - 1) / threads;
  hipLaunchKernelGGL(vqc_kernel, dim3(blocks), dim3(threads), 0, stream,
                     ang, thetas, out, B);
}

// Round 19
// 48.172 us; speedup vs baseline: 1.0395x; 1.0395x over previous
//
#include <hip/hip_runtime.h>

#define NQ 12
#define NL 4

typedef float f32x2 __attribute__((ext_vector_type(2)));

// ---------------------------------------------------------------------------
// Compile-time CNOT tracking as a GF(2) linear map (rounds 1-18, verified).
// RY(l,q) in tan form: mine'[i] = mine[i] + T(i)*mine[i^mk],
//   T(i) = +t iff parity(rm & i) odd else -t; cos factors -> Ctot^2 at end.
// LAYOUT (r9-r17, verified): TWO batch elements per wave.
//   physical lane = (elem << 5) | l5;  global index i = (l5 << 7) | (r<<1) | h
// ROUND 19: r17 source verbatim (best known, 48.1 us), ONE change — drop
// __syncthreads. The prep slab is per-wave (same-wave DS write->read is
// ordered via compiler-inserted lgkmcnt), so the barrier only forced 4-wave
// lockstep + full waitcnt drain (all waves hit DS-gate bursts together).
// ---------------------------------------------------------------------------
struct MaskTab { int mk[NL][NQ]; int rm[NL][NQ]; int rout[NQ]; };

static constexpr MaskTab build_masks() {
  MaskTab T{};
  unsigned col[NQ] = {};
  unsigned inv[NQ] = {};
  for (int k = 0; k < NQ; ++k) { col[k] = 1u << k; inv[k] = 1u << k; }
  for (int l = 0; l < NL; ++l) {
    for (int q = 0; q < NQ; ++q) {
      const int p = NQ - 1 - q;
      T.mk[l][q] = (int)inv[p];
      int rm = 0;
      for (int k = 0; k < NQ; ++k) rm |= (int)(((col[k] >> p) & 1u) << k);
      T.rm[l][q] = rm;
    }
    for (int q = 0; q < NQ - 1; ++q) {
      const int pc = NQ - 1 - q, pt = NQ - 2 - q;
      for (int k = 0; k < NQ; ++k) col[k] ^= ((col[k] >> pc) & 1u) << pt;
      inv[pc] ^= inv[pt];
    }
  }
  for (int q = 0; q < NQ; ++q) {
    const int p = NQ - 1 - q;
    int rm = 0;
    for (int k = 0; k < NQ; ++k) rm |= (int)(((col[k] >> p) & 1u) << k);
    T.rout[q] = rm;
  }
  return T;
}
static constexpr MaskTab MT = build_masks();

// ---------------- compile-time utils ----------------
constexpr int cpar(int j, int m) { return __builtin_popcount((unsigned)(j & m)) & 1; }
constexpr int chb(int m) { return m ? (1 << (31 - __builtin_clz((unsigned)m))) : 0; }
constexpr bool dpp_ok(int d) { return d==1||d==2||d==3||d==7||d==8||d==15; }
constexpr int dpp_ctrl_for(int d) {
  return d==1?0xB1 : d==2?0x4E : d==3?0x1B : d==7?0x141 : d==8?0x128 : 0x140;
}
// 2-DPP compositions kept on VALU: 6=7^1, 12=15^3 (5,10 stay on DS, as r17)
constexpr bool synth2_ok(int d) { return d==6||d==12; }
constexpr int synth_a(int d) { return d==6?0x141 : 0x140; }
constexpr int synth_b(int d) { return d==6?0xB1  : 0x1B; }

template <int V> struct ic_ { static constexpr int v = V; };
template <int I, int N, typename F>
__device__ __forceinline__ void sfor(F&& f) {
  if constexpr (I < N) { f(ic_<I>{}); sfor<I + 1, N>(f); }
}

// ---------------- cross-lane primitives ----------------
// r17-verified: single-instruction DPP mov (all source lanes active).
template <int CTRL>
__device__ __forceinline__ float dppf(float x) {
  return __int_as_float(__builtin_amdgcn_mov_dpp(__float_as_int(x), CTRL, 0xF, 0xF, false));
}
template <int PAT>
__device__ __forceinline__ float swzf(float x) {
  return __int_as_float(__builtin_amdgcn_ds_swizzle(__float_as_int(x), PAT));
}

__device__ __forceinline__ f32x2 pfma(f32x2 t, f32x2 p, f32x2 s) {
  return __builtin_elementwise_fma(t, p, s);
}

// lane-parity base sign: odd parity -> +t, even -> -t (rounds 2-18 verified).
template <int MASK>
__device__ __forceinline__ float lane_sign(float t, int lane) {
  if constexpr (MASK == 0) return -t;
  else return (__popc(lane & MASK) & 1) ? t : -t;
}

// ---------------- one RY gate (tan form), 2-elem layout ----------------
template <int L, int Q>
__device__ __forceinline__ void gate(f32x2 (&s2)[64], float t, int lane) {
  constexpr int MK  = MT.mk[L][Q];
  constexpr int RM  = MT.rm[L][Q];
  constexpr int MKL = (MK >> 7) & 31;   // lane-xor (physical lane bits 0-4)
  constexpr int MKO = MK & 127;         // register+half xor (index bits 0-6)
  constexpr int RMH = (RM >> 7) & 31;
  constexpr int RMO = RM & 127;
  const float tl  = lane_sign<RMH>(t, lane);
  const float tln = -tl;
  constexpr int M2 = MKO >> 1;   // f32x2-register xor
  constexpr int HS = MKO & 1;    // half swap (index bit 0)

  if constexpr (MKL == 0 && HS == 0) {
    // ---- packed register butterfly; RMO even -> per-register uniform sign ----
    f32x2 tp; tp.x = tl;  tp.y = tl;
    f32x2 tn; tn.x = tln; tn.y = tln;
    constexpr int HB = chb(M2);
    sfor<0, 64>([&](auto RC) {
      constexpr int r0 = decltype(RC)::v;
      if constexpr ((r0 & HB) == 0) {
        constexpr int r1 = r0 ^ M2;
        const f32x2 A = s2[r0], B = s2[r1];
        s2[r0] = pfma(cpar(2*r0, RMO) ? tn : tp, B, A);
        s2[r1] = pfma(cpar(2*r1, RMO) ? tn : tp, A, B);
      }
    });
  } else if constexpr (MKL == 0) {
    // ---- half-swap register gates: scalar FMAs ----
    if constexpr (M2 == 0) {
      sfor<0, 64>([&](auto RC) {
        constexpr int r = decltype(RC)::v;
        const float ax = s2[r].x, ay = s2[r].y;
        s2[r].x = fmaf(cpar(2*r,   RMO) ? tln : tl, ay, ax);
        s2[r].y = fmaf(cpar(2*r+1, RMO) ? tln : tl, ax, ay);
      });
    } else {
      constexpr int HB = chb(M2);
      sfor<0, 64>([&](auto RC) {
        constexpr int r0 = decltype(RC)::v;
        if constexpr ((r0 & HB) == 0) {
          constexpr int r1 = r0 ^ M2;
          const float ax = s2[r0].x, ay = s2[r0].y;
          const float bx = s2[r1].x, by = s2[r1].y;
          s2[r0].x = fmaf(cpar(2*r0,   RMO) ? tln : tl, by, ax);
          s2[r0].y = fmaf(cpar(2*r0+1, RMO) ? tln : tl, bx, ay);
          s2[r1].x = fmaf(cpar(2*r1,   RMO) ? tln : tl, ay, bx);
          s2[r1].y = fmaf(cpar(2*r1+1, RMO) ? tln : tl, ax, by);
        }
      });
    }
  } else if constexpr (dpp_ok(MKL) || synth2_ok(MKL)) {
    // ---- DPP-path cross gates: scalar tied-dst form (DPPCombine target) ----
    auto D = [&](float x) -> float {
      if constexpr (dpp_ok(MKL)) return dppf<dpp_ctrl_for(MKL)>(x);
      else return dppf<synth_b(MKL)>(dppf<synth_a(MKL)>(x));
    };
    if constexpr (M2 == 0) {
      sfor<0, 64>([&](auto RC) {
        constexpr int r = decltype(RC)::v;
        const float sr = cpar(2*r, RMO) ? tln : tl;
        s2[r].x = fmaf(D(s2[r].x), sr, s2[r].x);
        s2[r].y = fmaf(D(s2[r].y), sr, s2[r].y);
      });
    } else {
      constexpr int HB = chb(M2);
      sfor<0, 64>([&](auto RC) {
        constexpr int r0 = decltype(RC)::v;
        if constexpr ((r0 & HB) == 0) {
          constexpr int r1 = r0 ^ M2;
          const float s0v = cpar(2*r0, RMO) ? tln : tl;
          const float s1v = cpar(2*r1, RMO) ? tln : tl;
          const float ax = s2[r0].x, ay = s2[r0].y;
          const float bx = s2[r1].x, by = s2[r1].y;
          s2[r0].x = fmaf(D(bx), s0v, ax);
          s2[r0].y = fmaf(D(by), s0v, ay);
          s2[r1].x = fmaf(D(ax), s1v, bx);
          s2[r1].y = fmaf(D(ay), s1v, by);
        }
      });
    }
  } else {
    // ---- DS swizzle cross gates (masks 5,10,20,24,30; MKO even) ----
    constexpr int PAT = (MKL << 10) | 0x1F;
    f32x2 tp; tp.x = tl;  tp.y = tl;
    f32x2 tn; tn.x = tln; tn.y = tln;
    if constexpr (M2 == 0) {
      sfor<0, 64>([&](auto RC) {
        constexpr int r = decltype(RC)::v;
        f32x2 p; p.x = swzf<PAT>(s2[r].x); p.y = swzf<PAT>(s2[r].y);
        s2[r] = pfma(cpar(2*r, RMO) ? tn : tp, p, s2[r]);
      });
    } else {
      constexpr int HB = chb(M2);
      sfor<0, 64>([&](auto RC) {
        constexpr int r0 = decltype(RC)::v;
        if constexpr ((r0 & HB) == 0) {
          constexpr int r1 = r0 ^ M2;
          f32x2 pa; pa.x = swzf<PAT>(s2[r1].x); pa.y = swzf<PAT>(s2[r1].y);
          f32x2 pb; pb.x = swzf<PAT>(s2[r0].x); pb.y = swzf<PAT>(s2[r0].y);
          s2[r0] = pfma(cpar(2*r0, RMO) ? tn : tp, pa, s2[r0]);
          s2[r1] = pfma(cpar(2*r1, RMO) ? tn : tp, pb, s2[r1]);
        }
      });
    }
  }
}

template <int L, int Q>
__device__ __forceinline__ void round_rec(f32x2 (&s2)[64], const float (&t)[NQ], int lane) {
  if constexpr (Q < NQ) {
    gate<L, Q>(s2, t[Q], lane);
    round_rec<L, Q + 1>(s2, t, lane);
  }
}

__global__ __launch_bounds__(256, 2) void vqc_kernel(const float* __restrict__ ang,
                                                     const float* __restrict__ thetas,
                                                     float* __restrict__ out, int B) {
  const int tid  = blockIdx.x * blockDim.x + threadIdx.x;
  const int gw   = tid >> 6;          // wave index: elements 2gw, 2gw+1
  const int lane = tid & 63;
  const int l5   = lane & 31;
  const int elem = lane >> 5;
  const int row_store = 2 * gw + elem;
  const int row = (row_store < B) ? row_store : (B - 1);   // clamp

  // ---- distributed angle prep -> per-WAVE LDS slab (r10/r11 verified) ----
  // Same-wave write->read: compiler orders via lgkmcnt; no block barrier.
  // slab per element (64 floats): [0..35] tan(l=1..3,q), [36..47] c0, [48..59] s0
  __shared__ float prep[4][2][64];
  const int wib = threadIdx.x >> 6;
  float* P = &prep[wib][elem][0];

  float csprod;
  {
    const int tau1 = l5;
    const int lq1 = (1 + tau1 / 12) * NQ + (tau1 % 12);
    float sn, cs;
    __sincosf(0.5f * (ang[row * NQ + (tau1 % 12)] + thetas[lq1]), &sn, &cs);
    P[tau1] = __fdividef(sn, cs);
    csprod = cs;
    if (l5 < 16) {
      const int tau2 = l5 + 32;
      if (tau2 < 36) {
        const int q2 = tau2 % 12;
        float sn2, cs2;
        __sincosf(0.5f * (ang[row * NQ + q2] + thetas[3 * NQ + q2]), &sn2, &cs2);
        P[tau2] = __fdividef(sn2, cs2);
        csprod *= cs2;
      } else {
        const int q2 = tau2 - 36;
        float sn2, cs2;
        __sincosf(0.5f * (ang[row * NQ + q2] + thetas[q2]), &sn2, &cs2);
        P[36 + q2] = cs2;
        P[48 + q2] = sn2;
      }
    }
    csprod *= dppf<0xB1>(csprod);
    csprod *= dppf<0x4E>(csprod);
    csprod *= swzf<(4 << 10) | 0x1F>(csprod);
    csprod *= dppf<0x128>(csprod);
    csprod *= swzf<(16 << 10) | 0x1F>(csprod);
  }
  const float Csq = csprod * csprod;

  // vector read-back (broadcast reads, conflict-free; same-wave ordering)
  float t1[NQ], t2[NQ], t3[NQ], c0[NQ], s0[NQ];
  {
    const float4* P4 = (const float4*)P;
#define LD4(arr, base, idx) { float4 v = P4[idx]; arr[base]=v.x; arr[base+1]=v.y; arr[base+2]=v.z; arr[base+3]=v.w; }
    LD4(t1, 0, 0) LD4(t1, 4, 1) LD4(t1, 8, 2)
    LD4(t2, 0, 3) LD4(t2, 4, 4) LD4(t2, 8, 5)
    LD4(t3, 0, 6) LD4(t3, 4, 7) LD4(t3, 8, 8)
    LD4(c0, 0, 9) LD4(c0, 4, 10) LD4(c0, 8, 11)
    LD4(s0, 0, 12) LD4(s0, 4, 13) LD4(s0, 8, 14)
#undef LD4
  }

  // ---- layer 0 on |0..0>: per-element product state (rounds 9-17 verified) ----
  float flane = 1.0f;
  #pragma unroll
  for (int k = 0; k < 5; ++k) {
    flane *= ((l5 >> k) & 1) ? s0[4 - k] : c0[4 - k];
  }
  f32x2 s2[64];
  { f32x2 h0; h0.x = c0[11] * flane; h0.y = s0[11] * flane; s2[0] = h0; }
  #pragma unroll
  for (int k = 0; k < 6; ++k) {
    const int W = 1 << k;
    #pragma unroll
    for (int j = 0; j < 64; ++j) {
      if (j >= W) continue;
      s2[j + W] = s2[j] * s0[10 - k];
      s2[j]     = s2[j] * c0[10 - k];
    }
  }

  // ---- layers 1-3 (tan form) ----
  round_rec<1, 0>(s2, t1, lane);
  round_rec<2, 0>(s2, t2, lane);
  round_rec<3, 0>(s2, t3, lane);

  // probabilities (unscaled, packed)
  #pragma unroll
  for (int r = 0; r < 64; ++r) s2[r] = s2[r] * s2[r];

  // Walsh-Hadamard over the 7 register-dim bits
  #pragma unroll
  for (int r = 0; r < 64; ++r) {
    const float u = s2[r].x, v = s2[r].y;
    s2[r].x = u + v;
    s2[r].y = u - v;
  }
  #pragma unroll
  for (int b = 0; b < 6; ++b) {
    const int W = 1 << b;
    #pragma unroll
    for (int r0 = 0; r0 < 64; ++r0) {
      if (r0 & W) continue;
      const int r1 = r0 | W;
      const f32x2 u = s2[r0], v = s2[r1];
      s2[r0] = u + v;
      s2[r1] = u - v;
    }
  }

  // ---- epilogue: 12 signed reductions over lane bits 0-4 (per element) ----
  sfor<0, NQ>([&](auto QC) {
    constexpr int q   = decltype(QC)::v;
    constexpr int RM  = MT.rout[q];
    constexpr int RMH = (RM >> 7) & 31;
    constexpr int RMO = RM & 127;
    float v = (RMO & 1) ? s2[RMO >> 1].y : s2[RMO >> 1].x;
    if constexpr (RMH != 0) {
      const int sx = (__popc(lane & RMH) & 1) << 31;  // odd lane parity -> minus
      v = __int_as_float(__float_as_int(v) ^ sx);
    }
    v += dppf<0xB1>(v);               // xor1
    v += dppf<0x4E>(v);               // xor2
    v += swzf<(4 << 10) | 0x1F>(v);   // xor4
    v += dppf<0x128>(v);              // xor8
    v += swzf<(16 << 10) | 0x1F>(v);  // xor16 (within 32-lane group)
    if (l5 == 0 && row_store < B) out[row_store * NQ + q] = v * Csq;
  });
}

extern "C" void kernel_launch(void* const* d_in, const int* in_sizes, int n_in,
                              void* d_out, int out_size, void* d_ws, size_t ws_size,
                              hipStream_t stream) {
  const float* ang    = (const float*)d_in[0];
  const float* thetas = (const float*)d_in[1];
  float* out          = (float*)d_out;
  const int B = in_sizes[0] / NQ;
  const int waves = (B + 1) / 2;       // 2 elements per wave
  const int threads = 256;
  const int blocks = (waves * 64 + threads - 1) / threads;
  hipLaunchKernelGGL(vqc_kernel, dim3(blocks), dim3(threads), 0, stream,
                     ang, thetas, out, B);
}